// Round 9
// baseline (225.781 us; speedup 1.0000x reference)
//
#include <hip/hip_runtime.h>

// Exact-arithmetic replication of the JAX reference: no FMA contraction.
#pragma clang fp contract(off)

#define KK 12
#define EPS_Z 0.001f
#define BIG 1.0e10f

// JAX linspace(0,1,12): delta = f32(1/11) (one rounded division), t_k = k*delta.
#define T_DELTA (1.0f / 11.0f)

// Order-preserving float -> uint mapping (monotone for all finite floats,
// including negatives), so atomicMin(uint) == float min.
__device__ __forceinline__ unsigned int fmap(float f) {
    unsigned int u = __float_as_uint(f);
    return (u & 0x80000000u) ? ~u : (u | 0x80000000u);
}
__device__ __forceinline__ float funmap(unsigned int u) {
    return (u & 0x80000000u) ? __uint_as_float(u ^ 0x80000000u)
                             : __uint_as_float(~u);
}

__global__ void init_zbuf(unsigned int* __restrict__ zbuf,
                          const int* __restrict__ pH, const int* __restrict__ pW) {
    int total = pH[0] * pW[0];
    unsigned int v = fmap(BIG);
    for (int i = blockIdx.x * blockDim.x + threadIdx.x; i < total;
         i += gridDim.x * blockDim.x)
        zbuf[i] = v;
}

// One thread per (triangle, i) where i indexes the px sample (blockIdx.y).
// Each thread walks the 12 py samples.
__global__ void raster(const float* __restrict__ verts, const int* __restrict__ tris,
                       int T, const int* __restrict__ pH, const int* __restrict__ pW,
                       unsigned int* __restrict__ zbuf) {
#pragma clang fp contract(off)
    int t = blockIdx.x * blockDim.x + threadIdx.x;
    if (t >= T) return;
    const int i = blockIdx.y;
    const int W = pW[0];
    const int H = pH[0];
    const float Wm1 = (float)(W - 1);
    const float Hm1 = (float)(H - 1);

    int i0 = tris[t * 3 + 0], i1 = tris[t * 3 + 1], i2 = tris[t * 3 + 2];
    float x0 = verts[i0 * 3 + 0], y0 = verts[i0 * 3 + 1], z0 = verts[i0 * 3 + 2];
    float x1 = verts[i1 * 3 + 0], y1 = verts[i1 * 3 + 1], z1 = verts[i1 * 3 + 2];
    float x2 = verts[i2 * 3 + 0], y2 = verts[i2 * 3 + 1], z2 = verts[i2 * 3 + 2];

    // area exactly as reference
    float area = (x2 - x0) * (y1 - y0) - (y2 - y0) * (x1 - x0);
    if (!(fabsf(area) > 1e-8f)) return;  // all samples invalid -> BIG -> no-op

    float xmin = fminf(x0, fminf(x1, x2));
    float xmax = fmaxf(x0, fmaxf(x1, x2));
    float ymin = fminf(y0, fminf(y1, y2));
    float ymax = fmaxf(y0, fmaxf(y1, y2));

    // t_i = f32(i) * f32(1/11)  — matches jnp.linspace exactly (NOT i/11).
    float ti = (float)i * T_DELTA;
    float px = xmin + ti * (xmax - xmin);
    if (!(px >= 0.0f && px <= Wm1)) return;  // in_img fails for this whole column

    int ix = (int)fminf(fmaxf(rintf(px), 0.0f), Wm1);

    // Edge constants (hoisting products keeps identical f32 values).
    float e0dy = y2 - y1, e0dx = x2 - x1;  // edge(v1,v2)
    float e1dy = y0 - y2, e1dx = x0 - x2;  // edge(v2,v0)
    float e2dy = y1 - y0, e2dx = x1 - x0;  // edge(v0,v1)
    float a0 = (px - x1) * e0dy;
    float a1 = (px - x2) * e1dy;
    float a2 = (px - x0) * e2dy;

    float dy = ymax - ymin;
#pragma unroll
    for (int j = 0; j < KK; ++j) {
        float tj = (float)j * T_DELTA;  // compile-time, matches linspace
        float py = ymin + tj * dy;
        if (!(py >= 0.0f && py <= Hm1)) continue;
        float w0 = a0 - (py - y1) * e0dx;
        float w1 = a1 - (py - y2) * e1dx;
        float w2 = a2 - (py - y0) * e2dx;
        bool inside = (w0 >= 0.0f && w1 >= 0.0f && w2 >= 0.0f) ||
                      (w0 <= 0.0f && w1 <= 0.0f && w2 <= 0.0f);
        if (!inside) continue;
        float depth = ((w0 * z0 + w1 * z1) + w2 * z2) / area;  // left-assoc as XLA
        int iy = (int)fminf(fmaxf(rintf(py), 0.0f), Hm1);
        atomicMin(&zbuf[iy * W + ix], fmap(depth));
    }
}

__global__ void visible_k(const float* __restrict__ verts, int N,
                          const int* __restrict__ pH, const int* __restrict__ pW,
                          const unsigned int* __restrict__ zbuf,
                          float* __restrict__ out) {
#pragma clang fp contract(off)
    int n = blockIdx.x * blockDim.x + threadIdx.x;
    if (n >= N) return;
    const int W = pW[0];
    const int H = pH[0];
    const float Wm1 = (float)(W - 1);
    const float Hm1 = (float)(H - 1);
    float x = verts[n * 3 + 0], y = verts[n * 3 + 1], z = verts[n * 3 + 2];
    bool in_img = (x >= 0.0f) && (x <= Wm1) && (y >= 0.0f) && (y <= Hm1);
    float r = 0.0f;
    if (in_img) {
        int ix = (int)fminf(fmaxf(rintf(x), 0.0f), Wm1);
        int iy = (int)fminf(fmaxf(rintf(y), 0.0f), Hm1);
        float zb = funmap(zbuf[iy * W + ix]);
        r = (z <= zb + EPS_Z) ? 1.0f : 0.0f;
    }
    out[n] = r;
}

extern "C" void kernel_launch(void* const* d_in, const int* in_sizes, int n_in,
                              void* d_out, int out_size, void* d_ws, size_t ws_size,
                              hipStream_t stream) {
    const float* verts = (const float*)d_in[0];
    const int* tris = (const int*)d_in[1];
    const int* pH = (const int*)d_in[2];
    const int* pW = (const int*)d_in[3];
    int N = in_sizes[0] / 3;
    int T = in_sizes[1] / 3;
    unsigned int* zbuf = (unsigned int*)d_ws;  // H*W uints (1 MB at 512x512)

    init_zbuf<<<1024, 256, 0, stream>>>(zbuf, pH, pW);
    dim3 rgrid((T + 255) / 256, KK);
    raster<<<rgrid, 256, 0, stream>>>(verts, tris, T, pH, pW, zbuf);
    visible_k<<<(N + 255) / 256, 256, 0, stream>>>(verts, N, pH, pW, zbuf,
                                                   (float*)d_out);
}